// Round 3
// baseline (846.783 us; speedup 1.0000x reference)
//
#include <hip/hip_runtime.h>
#include <hip/hip_bf16.h>

#define SEQ 2048

__device__ __forceinline__ float silu_f(float x){ return x / (1.f + __expf(-x)); }

__device__ __forceinline__ float red16(float v){
    v += __shfl_xor(v, 1, 16);
    v += __shfl_xor(v, 2, 16);
    v += __shfl_xor(v, 4, 16);
    v += __shfl_xor(v, 8, 16);
    return v;
}

// ---------------- K0: transpose hidden (b,l,d) -> hidT (b,d,l), LDS 64x64 tile ----------------
__global__ __launch_bounds__(256) void k_transpose(const float* __restrict__ hid,
                                                   float* __restrict__ hidT){
    __shared__ float tile[64][65];
    int bid = blockIdx.x;                              // b*128 + lblk*4 + dblk ; 256 blocks
    int dblk = bid & 3; int lblk = (bid >> 2) & 31; int b = bid >> 7;
    int lane = threadIdx.x & 63; int row4 = threadIdx.x >> 6;
    #pragma unroll
    for (int r = 0; r < 16; ++r) {
        int lrow = row4 * 16 + r;
        tile[lrow][lane] = hid[((b * 2048) + lblk * 64 + lrow) * 256 + dblk * 64 + lane];
    }
    __syncthreads();
    #pragma unroll
    for (int r = 0; r < 16; ++r) {
        int drow = row4 * 16 + r;
        hidT[((b * 256) + dblk * 64 + drow) * 2048 + lblk * 64 + lane] = tile[lane][drow];
    }
}

// ---------------- K1: xz[b][e][l] = sum_d hidT[b][d][l] * in_w[e][d] ----------------
__global__ __launch_bounds__(256) void k_ingemm(const float* __restrict__ hidT,
                                                const float* __restrict__ in_w,
                                                float* __restrict__ xz){
    int lane = threadIdx.x & 63;
    int ew = threadIdx.x >> 6;                         // 0..3
    int bid = blockIdx.x;                              // 2 * 32 * 32
    int lblk = bid & 31; int eblk = (bid >> 5) & 31; int b = bid >> 10;
    int l = lblk * 64 + lane;
    int e0 = eblk * 32 + ew * 8;
    const float* hrow = hidT + b * 256 * SEQ + l;
    float acc[8] = {0,0,0,0,0,0,0,0};
    for (int d = 0; d < 256; d += 4) {
        float hv0 = hrow[(d + 0) * SEQ];
        float hv1 = hrow[(d + 1) * SEQ];
        float hv2 = hrow[(d + 2) * SEQ];
        float hv3 = hrow[(d + 3) * SEQ];
        #pragma unroll
        for (int k = 0; k < 8; ++k) {
            float4 wv = *(const float4*)(in_w + (e0 + k) * 256 + d);
            acc[k] = fmaf(wv.x, hv0, fmaf(wv.y, hv1, fmaf(wv.z, hv2, fmaf(wv.w, hv3, acc[k]))));
        }
    }
    #pragma unroll
    for (int k = 0; k < 8; ++k)
        xz[(b * 1024 + e0 + k) * SEQ + l] = acc[k];
}

// ---------------- K2: causal dwconv(K=4) + silu, permuted x staged via swizzled LDS ----------------
__global__ __launch_bounds__(256) void k_conv(const float* __restrict__ xz,
                                              const float* __restrict__ conv_w,
                                              const float* __restrict__ conv_b,
                                              float* __restrict__ u){
    __shared__ float xs[2112];                         // swizzle: addr = j + (j>>5)
    int row = blockIdx.x;                              // ib*512 + d, ib = i*2+b
    int d = row & 511; int ib = row >> 9; int b = ib & 1; int i = ib >> 1;
    const int shtab[3] = {11, 6, 4};
    int sh = shtab[i >> 1];
    int mul = SEQ >> sh;                               // 1, 32, 128
    int inv = 11 - sh;                                 // log2(mul)
    int flip = i & 1;
    float w0 = conv_w[(i * 512 + d) * 4 + 0];
    float w1 = conv_w[(i * 512 + d) * 4 + 1];
    float w2 = conv_w[(i * 512 + d) * 4 + 2];
    float w3 = conv_w[(i * 512 + d) * 4 + 3];
    float cb = conv_b[i * 512 + d];
    const float* xrow = xz + (b * 1024 + d) * SEQ;
    float* urow = u + row * SEQ;
    // stage: coalesced read in l-order, scatter to permuted-j position (swizzled)
    #pragma unroll
    for (int k = 0; k < 8; ++k) {
        int l = (int)threadIdx.x + k * 256;
        float v = xrow[l];
        int jj = ((l & (mul - 1)) << sh) | (l >> inv); // inverse interleave
        if (flip) jj = 2047 - jj;
        xs[jj + (jj >> 5)] = v;
    }
    __syncthreads();
    #pragma unroll
    for (int k = 0; k < 8; ++k) {
        int j = (int)threadIdx.x + k * 256;
        float acc = cb;
        #pragma unroll
        for (int m = 0; m < 4; ++m) {
            int idx = j - 3 + m;
            float xv = 0.f;
            if (idx >= 0) xv = xs[idx + (idx >> 5)];
            float wm = (m == 0) ? w0 : (m == 1) ? w1 : (m == 2) ? w2 : w3;
            acc = fmaf(wm, xv, acc);
        }
        urow[j] = silu_f(acc);
    }
}

// ---------------- K3: x_dbl[ib][r][j] = sum_d xproj_w[i][r][d] * u[ib][d][j] ----------------
__global__ __launch_bounds__(256) void k_xproj(const float* __restrict__ u,
                                               const float* __restrict__ xw,
                                               float* __restrict__ xdbl){
    int t = blockIdx.x * 256 + threadIdx.x;            // (ib*6+rb)*2048 + j ; 12*6*2048
    int j = t & 2047;
    int g = t >> 11;
    int rb = g % 6; int ib = g / 6; int i = ib >> 1;
    const float* ub = u + ib * 512 * SEQ + j;
    const float* wb = xw + (i * 48 + rb * 8) * 512;
    float acc[8] = {0,0,0,0,0,0,0,0};
    for (int dd = 0; dd < 512; dd += 4) {
        float u0 = ub[(dd + 0) * SEQ];
        float u1 = ub[(dd + 1) * SEQ];
        float u2 = ub[(dd + 2) * SEQ];
        float u3 = ub[(dd + 3) * SEQ];
        #pragma unroll
        for (int k2 = 0; k2 < 8; ++k2) {
            float4 wv = *(const float4*)(wb + k2 * 512 + dd);
            acc[k2] = fmaf(wv.x, u0, fmaf(wv.y, u1, fmaf(wv.z, u2, fmaf(wv.w, u3, acc[k2]))));
        }
    }
    float* ob = xdbl + (ib * 48 + rb * 8) * SEQ + j;
    #pragma unroll
    for (int k2 = 0; k2 < 8; ++k2) ob[k2 * SEQ] = acc[k2];
}

// ---------------- K4: delta[ib][d][j] = softplus(dtlow . dt_w[d] + dt_b[d]) ----------------
__global__ __launch_bounds__(256) void k_delta(const float* __restrict__ xdbl,
                                               const float* __restrict__ dt_w,
                                               const float* __restrict__ dt_b,
                                               float* __restrict__ delta){
    int t = blockIdx.x * 256 + threadIdx.x;            // (ib*128 + d4)*2048 + j
    int j = t & 2047;
    int d4 = (t >> 11) & 127;
    int ib = t >> 18; int i = ib >> 1;
    const float* dl = xdbl + ib * 48 * SEQ + j;        // dtlow rows r=0..15
    const float* w = dt_w + (i * 512 + d4 * 4) * 16;
    float a0 = 0, a1 = 0, a2 = 0, a3 = 0;
    #pragma unroll
    for (int r = 0; r < 16; ++r) {
        float v = dl[r * SEQ];
        a0 = fmaf(w[r],      v, a0);
        a1 = fmaf(w[16 + r], v, a1);
        a2 = fmaf(w[32 + r], v, a2);
        a3 = fmaf(w[48 + r], v, a3);
    }
    float accs[4] = {a0, a1, a2, a3};
    #pragma unroll
    for (int k = 0; k < 4; ++k) {
        float x = accs[k] + dt_b[i * 512 + d4 * 4 + k];
        // stable fast softplus: max(x,0) + log(1 + exp(-|x|))
        float sp = fmaxf(x, 0.f) + __logf(1.f + __expf(-fabsf(x)));
        delta[(ib * 512 + d4 * 4 + k) * SEQ + j] = sp;
    }
}

// ---------------- K5: SSM scan, block-factored (chain = 1 fma / 4 steps), depth-2 prefetch ----------------
__global__ __launch_bounds__(256) void k_scan(float* __restrict__ u,
                                              const float* __restrict__ delta,
                                              const float* __restrict__ xdbl,
                                              const float* __restrict__ A_log,
                                              const float* __restrict__ D_skip){
    int gid = blockIdx.x * 256 + threadIdx.x;
    int w = gid >> 4;                                  // worker: ib*512 + d
    int n = gid & 15;                                  // state
    int d = w & 511; int ib = w >> 9; int i = ib >> 1;
    float A = -__expf(A_log[(i * 512 + d) * 16 + n]);
    float Dd = D_skip[i * 512 + d];
    const float4* d4 = (const float4*)(delta + (size_t)w * SEQ);
    float4* u4 = (float4*)(u + (size_t)w * SEQ);
    const float4* B4 = (const float4*)(xdbl + (ib * 48 + 16 + n) * SEQ);
    const float4* C4 = (const float4*)(xdbl + (ib * 48 + 32 + n) * SEQ);
    float h = 0.f;
    // depth-2 pipeline (over-reads <=2 blocks past row end: stays inside ws)
    float4 dv0 = d4[0], uv0 = u4[0], Bv0 = B4[0], Cv0 = C4[0];
    float4 dv1 = d4[1], uv1 = u4[1], Bv1 = B4[1], Cv1 = C4[1];
    for (int jb = 0; jb < SEQ / 4; ++jb) {
        float4 dv2 = d4[jb + 2];
        float4 uv2 = u4[jb + 2];
        float4 Bv2 = B4[jb + 2];
        float4 Cv2 = C4[jb + 2];
        // off-chain: exps, inputs, local prefix scans
        float e1 = __expf(dv0.x * A), e2 = __expf(dv0.y * A);
        float e3 = __expf(dv0.z * A), e4 = __expf(dv0.w * A);
        float x1 = dv0.x * uv0.x * Bv0.x;
        float x2 = dv0.y * uv0.y * Bv0.y;
        float x3 = dv0.z * uv0.z * Bv0.z;
        float x4 = dv0.w * uv0.w * Bv0.w;
        float s2 = fmaf(e2, x1, x2);
        float s3 = fmaf(e3, s2, x3);
        float s4 = fmaf(e4, s3, x4);
        float c2 = e2 * e1;
        float c3 = e3 * c2;
        float c4 = e4 * c3;
        // on-chain: one fma each off prior h (independent of each other)
        float h1 = fmaf(e1, h, x1);
        float h2 = fmaf(c2, h, s2);
        float h3 = fmaf(c3, h, s3);
        float h4 = fmaf(c4, h, s4);
        h = h4;
        float y1 = red16(h1 * Cv0.x);
        float y2 = red16(h2 * Cv0.y);
        float y3 = red16(h3 * Cv0.z);
        float y4 = red16(h4 * Cv0.w);
        if (n == 0) {
            float4 yo;
            yo.x = fmaf(uv0.x, Dd, y1);
            yo.y = fmaf(uv0.y, Dd, y2);
            yo.z = fmaf(uv0.z, Dd, y3);
            yo.w = fmaf(uv0.w, Dd, y4);
            u4[jb] = yo;
        }
        dv0 = dv1; uv0 = uv1; Bv0 = Bv1; Cv0 = Cv1;
        dv1 = dv2; uv1 = uv2; Bv1 = Bv2; Cv1 = Cv2;
    }
}

// ---------------- K6: un-permute, sum branches, silu(z) fused; LDS-staged permuted rows ----------------
__global__ __launch_bounds__(256) void k_gather(const float* __restrict__ y,
                                                const float* __restrict__ xz,
                                                float* __restrict__ total){
    __shared__ float s2[2112], s3[2112], s4[2112], s5[2112];
    int bid = blockIdx.x;                              // b*512 + d ; 1024 blocks
    int d = bid & 511; int b = bid >> 9;
    long base = (long)(b * 512 + d) * SEQ;
    const float* y0 = y + (0 * 1024) * SEQ + base;
    const float* y1 = y + (1 * 1024) * SEQ + base;
    const float* y2r = y + (2 * 1024) * SEQ + base;
    const float* y3r = y + (3 * 1024) * SEQ + base;
    const float* y4r = y + (4 * 1024) * SEQ + base;
    const float* y5r = y + (5 * 1024) * SEQ + base;
    #pragma unroll
    for (int k = 0; k < 8; ++k) {
        int j = (int)threadIdx.x + k * 256;
        int a = j + (j >> 5);
        s2[a] = y2r[j];
        s3[a] = y3r[j];
        s4[a] = y4r[j];
        s5[a] = y5r[j];
    }
    __syncthreads();
    const float* zrow = xz + (b * 1024 + 512 + d) * SEQ;
    float* trow = total + (b * 512 + d) * SEQ;
    #pragma unroll
    for (int k = 0; k < 8; ++k) {
        int l = (int)threadIdx.x + k * 256;
        int j2 = ((l & 31) << 6) | (l >> 5);           // interleave ns=64 read index
        int j4 = ((l & 127) << 4) | (l >> 7);          // interleave ns=16 read index
        int a2 = j2 + (j2 >> 5);
        int a4 = j4 + (j4 >> 5);
        float s_fwd = y0[l] + y1[2047 - l] + s2[a2] + s4[a4];
        float s_bwd = s3[a2] + s5[a4];
        float zl = silu_f(zrow[l]);
        float zr = silu_f(zrow[2047 - l]);
        trow[l] = fmaf(s_fwd, zl, s_bwd * zr);
    }
}

// ---------------- K7: out[b][l][o] = sum_d total[b][d][l] * out_w[o][d] ----------------
__global__ __launch_bounds__(256) void k_outgemm(const float* __restrict__ total,
                                                 const float* __restrict__ out_w,
                                                 float* __restrict__ out){
    int lane = threadIdx.x & 63;
    int ow = threadIdx.x >> 6;                         // 0..3
    int bid = blockIdx.x;                              // 2*8*32
    int lblk = bid & 31; int oblk = (bid >> 5) & 7; int b = bid >> 8;
    int l = lblk * 64 + lane;
    int o0 = oblk * 32 + ow * 8;
    const float* trow = total + b * 512 * SEQ + l;
    float acc[8] = {0,0,0,0,0,0,0,0};
    for (int d = 0; d < 512; d += 4) {
        float t0 = trow[(d + 0) * SEQ];
        float t1 = trow[(d + 1) * SEQ];
        float t2 = trow[(d + 2) * SEQ];
        float t3 = trow[(d + 3) * SEQ];
        #pragma unroll
        for (int k = 0; k < 8; ++k) {
            float4 wv = *(const float4*)(out_w + (o0 + k) * 512 + d);
            acc[k] = fmaf(wv.x, t0, fmaf(wv.y, t1, fmaf(wv.z, t2, fmaf(wv.w, t3, acc[k]))));
        }
    }
    float* orow = out + ((long)(b * 2048 + l)) * 256 + o0;
    #pragma unroll
    for (int k = 0; k < 8; ++k) orow[k] = acc[k];
}

extern "C" void kernel_launch(void* const* d_in, const int* in_sizes, int n_in,
                              void* d_out, int out_size, void* d_ws, size_t ws_size,
                              hipStream_t stream) {
    const float* hid    = (const float*)d_in[0];
    const float* in_w   = (const float*)d_in[1];
    const float* out_w  = (const float*)d_in[2];
    const float* conv_w = (const float*)d_in[3];
    const float* conv_b = (const float*)d_in[4];
    const float* xw     = (const float*)d_in[5];
    const float* dt_w   = (const float*)d_in[6];
    const float* dt_b   = (const float*)d_in[7];
    const float* A_log  = (const float*)d_in[8];
    const float* D_skip = (const float*)d_in[9];
    float* out = (float*)d_out;

    // ws layout (floats)
    const size_t off_xz    = 0;                        // 2*1024*2048  = 4,194,304
    const size_t off_u     = 4194304;                  // 12*512*2048  = 12,582,912
    const size_t off_xdbl  = 16777216;                 // 12*48*2048   = 1,179,648
    const size_t off_delta = 17956864;                 // 12,582,912
    const size_t off_total = 30539776;                 // 2*512*2048   = 2,097,152
    const size_t need = (size_t)32636928 * 4;
    if (ws_size < need) return;

    float* xz    = (float*)d_ws + off_xz;
    float* u     = (float*)d_ws + off_u;
    float* xdbl  = (float*)d_ws + off_xdbl;
    float* delta = (float*)d_ws + off_delta;
    float* total = (float*)d_ws + off_total;
    float* hidT  = total;                              // alias: free until k_gather

    k_transpose<<<256,  256, 0, stream>>>(hid, hidT);
    k_ingemm  <<<2048, 256, 0, stream>>>(hidT, in_w, xz);
    k_conv    <<<6144, 256, 0, stream>>>(xz, conv_w, conv_b, u);
    k_xproj   <<<576,  256, 0, stream>>>(u, xw, xdbl);
    k_delta   <<<12288,256, 0, stream>>>(xdbl, dt_w, dt_b, delta);
    k_scan    <<<384,  256, 0, stream>>>(u, delta, xdbl, A_log, D_skip);
    k_gather  <<<1024, 256, 0, stream>>>(u, xz, total);
    k_outgemm <<<512,  256, 0, stream>>>(total, out_w, out);
}

// Round 4
// 700.317 us; speedup vs baseline: 1.2091x; 1.2091x over previous
//
#include <hip/hip_runtime.h>
#include <hip/hip_bf16.h>

#define SEQ 2048

__device__ __forceinline__ float silu_f(float x){ return x / (1.f + __expf(-x)); }

__device__ __forceinline__ float red16(float v){
    v += __shfl_xor(v, 1, 16);
    v += __shfl_xor(v, 2, 16);
    v += __shfl_xor(v, 4, 16);
    v += __shfl_xor(v, 8, 16);
    return v;
}

// ---------------- K0: transpose hidden (b,l,d) -> hidT (b,d,l), LDS 64x64 tile ----------------
__global__ __launch_bounds__(256) void k_transpose(const float* __restrict__ hid,
                                                   float* __restrict__ hidT){
    __shared__ float tile[64][65];
    int bid = blockIdx.x;                              // b*128 + lblk*4 + dblk ; 256 blocks
    int dblk = bid & 3; int lblk = (bid >> 2) & 31; int b = bid >> 7;
    int lane = threadIdx.x & 63; int row4 = threadIdx.x >> 6;
    #pragma unroll
    for (int r = 0; r < 16; ++r) {
        int lrow = row4 * 16 + r;
        tile[lrow][lane] = hid[((b * 2048) + lblk * 64 + lrow) * 256 + dblk * 64 + lane];
    }
    __syncthreads();
    #pragma unroll
    for (int r = 0; r < 16; ++r) {
        int drow = row4 * 16 + r;
        hidT[((b * 256) + dblk * 64 + drow) * 2048 + lblk * 64 + lane] = tile[lane][drow];
    }
}

// ---------------- K1: xz[b][e][l] = sum_d hidT[b][d][l] * in_w[e][d] ----------------
__global__ __launch_bounds__(256) void k_ingemm(const float* __restrict__ hidT,
                                                const float* __restrict__ in_w,
                                                float* __restrict__ xz){
    int lane = threadIdx.x & 63;
    int ew = threadIdx.x >> 6;                         // 0..3
    int bid = blockIdx.x;                              // 2 * 32 * 32
    int lblk = bid & 31; int eblk = (bid >> 5) & 31; int b = bid >> 10;
    int l = lblk * 64 + lane;
    int e0 = eblk * 32 + ew * 8;
    const float* hrow = hidT + b * 256 * SEQ + l;
    float acc[8] = {0,0,0,0,0,0,0,0};
    for (int d = 0; d < 256; d += 4) {
        float hv0 = hrow[(d + 0) * SEQ];
        float hv1 = hrow[(d + 1) * SEQ];
        float hv2 = hrow[(d + 2) * SEQ];
        float hv3 = hrow[(d + 3) * SEQ];
        #pragma unroll
        for (int k = 0; k < 8; ++k) {
            float4 wv = *(const float4*)(in_w + (e0 + k) * 256 + d);
            acc[k] = fmaf(wv.x, hv0, fmaf(wv.y, hv1, fmaf(wv.z, hv2, fmaf(wv.w, hv3, acc[k]))));
        }
    }
    #pragma unroll
    for (int k = 0; k < 8; ++k)
        xz[(b * 1024 + e0 + k) * SEQ + l] = acc[k];
}

// ---------------- K2: causal dwconv(K=4) + silu, permuted x staged via swizzled LDS ----------------
__global__ __launch_bounds__(256) void k_conv(const float* __restrict__ xz,
                                              const float* __restrict__ conv_w,
                                              const float* __restrict__ conv_b,
                                              float* __restrict__ u){
    __shared__ float xs[2112];                         // swizzle: addr = j + (j>>5)
    int row = blockIdx.x;                              // ib*512 + d, ib = i*2+b
    int d = row & 511; int ib = row >> 9; int b = ib & 1; int i = ib >> 1;
    const int shtab[3] = {11, 6, 4};
    int sh = shtab[i >> 1];
    int mul = SEQ >> sh;                               // 1, 32, 128
    int inv = 11 - sh;                                 // log2(mul)
    int flip = i & 1;
    float w0 = conv_w[(i * 512 + d) * 4 + 0];
    float w1 = conv_w[(i * 512 + d) * 4 + 1];
    float w2 = conv_w[(i * 512 + d) * 4 + 2];
    float w3 = conv_w[(i * 512 + d) * 4 + 3];
    float cb = conv_b[i * 512 + d];
    const float* xrow = xz + (b * 1024 + d) * SEQ;
    float* urow = u + row * SEQ;
    #pragma unroll
    for (int k = 0; k < 8; ++k) {
        int l = (int)threadIdx.x + k * 256;
        float v = xrow[l];
        int jj = ((l & (mul - 1)) << sh) | (l >> inv); // inverse interleave
        if (flip) jj = 2047 - jj;
        xs[jj + (jj >> 5)] = v;
    }
    __syncthreads();
    #pragma unroll
    for (int k = 0; k < 8; ++k) {
        int j = (int)threadIdx.x + k * 256;
        float acc = cb;
        #pragma unroll
        for (int m = 0; m < 4; ++m) {
            int idx = j - 3 + m;
            float xv = 0.f;
            if (idx >= 0) xv = xs[idx + (idx >> 5)];
            float wm = (m == 0) ? w0 : (m == 1) ? w1 : (m == 2) ? w2 : w3;
            acc = fmaf(wm, xv, acc);
        }
        urow[j] = silu_f(acc);
    }
}

// ---------------- K3: x_dbl[ib][r][j] = sum_d xproj_w[i][r][d] * u[ib][d][j] ----------------
__global__ __launch_bounds__(256) void k_xproj(const float* __restrict__ u,
                                               const float* __restrict__ xw,
                                               float* __restrict__ xdbl){
    int t = blockIdx.x * 256 + threadIdx.x;            // (ib*6+rb)*2048 + j ; 12*6*2048
    int j = t & 2047;
    int g = t >> 11;
    int rb = g % 6; int ib = g / 6; int i = ib >> 1;
    const float* ub = u + ib * 512 * SEQ + j;
    const float* wb = xw + (i * 48 + rb * 8) * 512;
    float acc[8] = {0,0,0,0,0,0,0,0};
    for (int dd = 0; dd < 512; dd += 4) {
        float u0 = ub[(dd + 0) * SEQ];
        float u1 = ub[(dd + 1) * SEQ];
        float u2 = ub[(dd + 2) * SEQ];
        float u3 = ub[(dd + 3) * SEQ];
        #pragma unroll
        for (int k2 = 0; k2 < 8; ++k2) {
            float4 wv = *(const float4*)(wb + k2 * 512 + dd);
            acc[k2] = fmaf(wv.x, u0, fmaf(wv.y, u1, fmaf(wv.z, u2, fmaf(wv.w, u3, acc[k2]))));
        }
    }
    float* ob = xdbl + (ib * 48 + rb * 8) * SEQ + j;
    #pragma unroll
    for (int k2 = 0; k2 < 8; ++k2) ob[k2 * SEQ] = acc[k2];
}

// ---------------- K3b: transpose B/C rows to btct[ib][j][32] (B: q=0..15, C: q=16..31) ----------------
__global__ __launch_bounds__(256) void k_btct(const float* __restrict__ xdbl,
                                              float* __restrict__ btct){
    int t = blockIdx.x * 256 + threadIdx.x;            // 12*32*2048 = 786432
    int j = t & 2047; int q = (t >> 11) & 31; int ib = t >> 16;
    btct[((ib * 2048 + j) << 5) + q] = xdbl[(ib * 48 + 16 + q) * 2048 + j];
}

// ---------------- K4: delta[ib][d][j] = softplus(dtlow . dt_w[d] + dt_b[d]) ----------------
__global__ __launch_bounds__(256) void k_delta(const float* __restrict__ xdbl,
                                               const float* __restrict__ dt_w,
                                               const float* __restrict__ dt_b,
                                               float* __restrict__ delta){
    int t = blockIdx.x * 256 + threadIdx.x;            // (ib*128 + d4)*2048 + j
    int j = t & 2047;
    int d4 = (t >> 11) & 127;
    int ib = t >> 18; int i = ib >> 1;
    const float* dl = xdbl + ib * 48 * SEQ + j;        // dtlow rows r=0..15
    const float* w = dt_w + (i * 512 + d4 * 4) * 16;
    float a0 = 0, a1 = 0, a2 = 0, a3 = 0;
    #pragma unroll
    for (int r = 0; r < 16; ++r) {
        float v = dl[r * SEQ];
        a0 = fmaf(w[r],      v, a0);
        a1 = fmaf(w[16 + r], v, a1);
        a2 = fmaf(w[32 + r], v, a2);
        a3 = fmaf(w[48 + r], v, a3);
    }
    float accs[4] = {a0, a1, a2, a3};
    #pragma unroll
    for (int k = 0; k < 4; ++k) {
        float x = accs[k] + dt_b[i * 512 + d4 * 4 + k];
        float sp = fmaxf(x, 0.f) + __logf(1.f + __expf(-fabsf(x)));
        delta[(ib * 512 + d4 * 4 + k) * SEQ + j] = sp;
    }
}

// ---------------- K5: chunked SSM scan. Block = one worker (ib,d); 16 chunks x 16 states ----------------
// Phase 1: per-chunk local scan (h0=0) -> (h_end, sum delta). Phase 2: 16-step serial
// cross-chunk combine using decay product exp(A * sum_delta). Phase 3: rescan with true h0,
// y via 16-lane reduce. delta/u staged in LDS; y written over u staging, coalesced writeback.
__global__ __launch_bounds__(256) void k_scan(float* __restrict__ u,
                                              const float* __restrict__ delta,
                                              const float* __restrict__ xdbl_unused,
                                              const float* __restrict__ btct,
                                              const float* __restrict__ A_log,
                                              const float* __restrict__ D_skip){
    __shared__ float4 sdelta4[512];                    // 2048 floats
    __shared__ float4 su4[512];                        // 2048 floats; reused for y output
    __shared__ float sh[256];                          // h_end[cc][n]
    __shared__ float sh0[256];                         // h0[cc][n]
    __shared__ float sS[16];                           // sum(delta) per chunk
    int w = blockIdx.x;                                // ib*512 + d
    int tid = threadIdx.x;
    int cc = tid >> 4;                                 // chunk 0..15
    int n  = tid & 15;                                 // state 0..15
    int d = w & 511; int ib = w >> 9; int i = ib >> 1;
    float A = -__expf(A_log[(i * 512 + d) * 16 + n]);
    float Dd = D_skip[i * 512 + d];

    const float4* dg4 = (const float4*)(delta + (size_t)w * SEQ);
    float4* ug4 = (float4*)(u + (size_t)w * SEQ);
    sdelta4[tid]       = dg4[tid];
    sdelta4[tid + 256] = dg4[tid + 256];
    su4[tid]           = ug4[tid];
    su4[tid + 256]     = ug4[tid + 256];
    __syncthreads();

    const float* sdelta = (const float*)sdelta4;
    float* su = (float*)su4;
    const float* bp = btct + ((size_t)(ib * 2048 + cc * 128) << 5) + n;  // [j][32], B at +0, C at +16

    // Phase 1: local scan, h0 = 0
    float h = 0.f, S = 0.f;
    int jbase = cc * 128;
    #pragma unroll 4
    for (int t = 0; t < 128; ++t) {
        float dlt = sdelta[jbase + t];
        float uu  = su[jbase + t];
        float b   = bp[t * 32];
        float e = __expf(dlt * A);
        h = fmaf(e, h, dlt * uu * b);
        S += dlt;
    }
    sh[cc * 16 + n] = h;
    if (n == 0) sS[cc] = S;
    __syncthreads();

    // Phase 2: serial cross-chunk combine (threads 0..15, one per state)
    if (tid < 16) {
        float h0 = 0.f;
        #pragma unroll
        for (int c = 0; c < 16; ++c) {
            sh0[c * 16 + tid] = h0;
            h0 = fmaf(__expf(A * sS[c]), h0, sh[c * 16 + tid]);
        }
    }
    __syncthreads();

    // Phase 3: rescan with true h0; y = red16(h*C); overwrite su with y
    h = sh0[cc * 16 + n];
    #pragma unroll 4
    for (int t = 0; t < 128; ++t) {
        float dlt = sdelta[jbase + t];
        float uu  = su[jbase + t];
        float b   = bp[t * 32];
        float cv  = bp[t * 32 + 16];
        float e = __expf(dlt * A);
        h = fmaf(e, h, dlt * uu * b);
        float y = red16(h * cv);
        if (n == 0) su[jbase + t] = fmaf(uu, Dd, y);
    }
    __syncthreads();

    ug4[tid]       = su4[tid];
    ug4[tid + 256] = su4[tid + 256];
}

// ---------------- K6: un-permute, sum branches, silu(z) fused; LDS-staged permuted rows ----------------
__global__ __launch_bounds__(256) void k_gather(const float* __restrict__ y,
                                                const float* __restrict__ xz,
                                                float* __restrict__ total){
    __shared__ float s2[2112], s3[2112], s4[2112], s5[2112];
    int bid = blockIdx.x;                              // b*512 + d ; 1024 blocks
    int d = bid & 511; int b = bid >> 9;
    long base = (long)(b * 512 + d) * SEQ;
    const float* y0 = y + (0 * 1024) * SEQ + base;
    const float* y1 = y + (1 * 1024) * SEQ + base;
    const float* y2r = y + (2 * 1024) * SEQ + base;
    const float* y3r = y + (3 * 1024) * SEQ + base;
    const float* y4r = y + (4 * 1024) * SEQ + base;
    const float* y5r = y + (5 * 1024) * SEQ + base;
    #pragma unroll
    for (int k = 0; k < 8; ++k) {
        int j = (int)threadIdx.x + k * 256;
        int a = j + (j >> 5);
        s2[a] = y2r[j];
        s3[a] = y3r[j];
        s4[a] = y4r[j];
        s5[a] = y5r[j];
    }
    __syncthreads();
    const float* zrow = xz + (b * 1024 + 512 + d) * SEQ;
    float* trow = total + (b * 512 + d) * SEQ;
    #pragma unroll
    for (int k = 0; k < 8; ++k) {
        int l = (int)threadIdx.x + k * 256;
        int j2 = ((l & 31) << 6) | (l >> 5);           // interleave ns=64 read index
        int j4 = ((l & 127) << 4) | (l >> 7);          // interleave ns=16 read index
        int a2 = j2 + (j2 >> 5);
        int a4 = j4 + (j4 >> 5);
        float s_fwd = y0[l] + y1[2047 - l] + s2[a2] + s4[a4];
        float s_bwd = s3[a2] + s5[a4];
        float zl = silu_f(zrow[l]);
        float zr = silu_f(zrow[2047 - l]);
        trow[l] = fmaf(s_fwd, zl, s_bwd * zr);
    }
}

// ---------------- K7: out[b][l][o] = sum_d total[b][d][l] * out_w[o][d] ----------------
__global__ __launch_bounds__(256) void k_outgemm(const float* __restrict__ total,
                                                 const float* __restrict__ out_w,
                                                 float* __restrict__ out){
    int lane = threadIdx.x & 63;
    int ow = threadIdx.x >> 6;                         // 0..3
    int bid = blockIdx.x;                              // 2*8*32
    int lblk = bid & 31; int oblk = (bid >> 5) & 7; int b = bid >> 8;
    int l = lblk * 64 + lane;
    int o0 = oblk * 32 + ow * 8;
    const float* trow = total + b * 512 * SEQ + l;
    float acc[8] = {0,0,0,0,0,0,0,0};
    for (int d = 0; d < 512; d += 4) {
        float t0 = trow[(d + 0) * SEQ];
        float t1 = trow[(d + 1) * SEQ];
        float t2 = trow[(d + 2) * SEQ];
        float t3 = trow[(d + 3) * SEQ];
        #pragma unroll
        for (int k = 0; k < 8; ++k) {
            float4 wv = *(const float4*)(out_w + (o0 + k) * 512 + d);
            acc[k] = fmaf(wv.x, t0, fmaf(wv.y, t1, fmaf(wv.z, t2, fmaf(wv.w, t3, acc[k]))));
        }
    }
    float* orow = out + ((long)(b * 2048 + l)) * 256 + o0;
    #pragma unroll
    for (int k = 0; k < 8; ++k) orow[k] = acc[k];
}

extern "C" void kernel_launch(void* const* d_in, const int* in_sizes, int n_in,
                              void* d_out, int out_size, void* d_ws, size_t ws_size,
                              hipStream_t stream) {
    const float* hid    = (const float*)d_in[0];
    const float* in_w   = (const float*)d_in[1];
    const float* out_w  = (const float*)d_in[2];
    const float* conv_w = (const float*)d_in[3];
    const float* conv_b = (const float*)d_in[4];
    const float* xw     = (const float*)d_in[5];
    const float* dt_w   = (const float*)d_in[6];
    const float* dt_b   = (const float*)d_in[7];
    const float* A_log  = (const float*)d_in[8];
    const float* D_skip = (const float*)d_in[9];
    float* out = (float*)d_out;

    // ws layout (floats)
    const size_t off_xz    = 0;                        // 2*1024*2048  = 4,194,304
    const size_t off_u     = 4194304;                  // 12*512*2048  = 12,582,912
    const size_t off_xdbl  = 16777216;                 // 12*48*2048   = 1,179,648
    const size_t off_delta = 17956864;                 // 12,582,912
    const size_t off_total = 30539776;                 // 2*512*2048   = 2,097,152
    const size_t need = (size_t)32636928 * 4;
    if (ws_size < need) return;

    float* xz    = (float*)d_ws + off_xz;
    float* u     = (float*)d_ws + off_u;
    float* xdbl  = (float*)d_ws + off_xdbl;
    float* delta = (float*)d_ws + off_delta;
    float* total = (float*)d_ws + off_total;
    // total region (2.1M floats) is time-shared: hidT (until k_ingemm) ->
    // btct (786K floats, k_btct..k_scan) -> total (k_gather..k_outgemm)
    float* hidT  = total;
    float* btct  = total;

    k_transpose<<<256,  256, 0, stream>>>(hid, hidT);
    k_ingemm  <<<2048, 256, 0, stream>>>(hidT, in_w, xz);
    k_conv    <<<6144, 256, 0, stream>>>(xz, conv_w, conv_b, u);
    k_xproj   <<<576,  256, 0, stream>>>(u, xw, xdbl);
    k_delta   <<<12288,256, 0, stream>>>(xdbl, dt_w, dt_b, delta);
    k_btct    <<<3072, 256, 0, stream>>>(xdbl, btct);
    k_scan    <<<6144, 256, 0, stream>>>(u, delta, xdbl, btct, A_log, D_skip);
    k_gather  <<<1024, 256, 0, stream>>>(u, xz, total);
    k_outgemm <<<512,  256, 0, stream>>>(total, out_w, out);
}

// Round 6
// 628.119 us; speedup vs baseline: 1.3481x; 1.1149x over previous
//
#include <hip/hip_runtime.h>
#include <hip/hip_bf16.h>

#define SEQ 2048

__device__ __forceinline__ float silu_f(float x){ return x / (1.f + __expf(-x)); }

__device__ __forceinline__ float red16(float v){
    v += __shfl_xor(v, 1, 16);
    v += __shfl_xor(v, 2, 16);
    v += __shfl_xor(v, 4, 16);
    v += __shfl_xor(v, 8, 16);
    return v;
}

// ---------------- K0: transpose hidden (b,l,d) -> hidT (b,d,l), LDS 64x64 tile ----------------
__global__ __launch_bounds__(256) void k_transpose(const float* __restrict__ hid,
                                                   float* __restrict__ hidT){
    __shared__ float tile[64][65];
    int bid = blockIdx.x;                              // b*128 + lblk*4 + dblk ; 256 blocks
    int dblk = bid & 3; int lblk = (bid >> 2) & 31; int b = bid >> 7;
    int lane = threadIdx.x & 63; int row4 = threadIdx.x >> 6;
    #pragma unroll
    for (int r = 0; r < 16; ++r) {
        int lrow = row4 * 16 + r;
        tile[lrow][lane] = hid[((b * 2048) + lblk * 64 + lrow) * 256 + dblk * 64 + lane];
    }
    __syncthreads();
    #pragma unroll
    for (int r = 0; r < 16; ++r) {
        int drow = row4 * 16 + r;
        hidT[((b * 256) + dblk * 64 + drow) * 2048 + lblk * 64 + lane] = tile[lane][drow];
    }
}

// ---------------- K1: xz[b][e][l] = sum_d hidT[b][d][l] * in_w[e][d] ----------------
__global__ __launch_bounds__(256) void k_ingemm(const float* __restrict__ hidT,
                                                const float* __restrict__ in_w,
                                                float* __restrict__ xz){
    int lane = threadIdx.x & 63;
    int ew = threadIdx.x >> 6;                         // 0..3
    int bid = blockIdx.x;                              // 2 * 32 * 32
    int lblk = bid & 31; int eblk = (bid >> 5) & 31; int b = bid >> 10;
    int l = lblk * 64 + lane;
    int e0 = eblk * 32 + ew * 8;
    const float* hrow = hidT + b * 256 * SEQ + l;
    float acc[8] = {0,0,0,0,0,0,0,0};
    for (int d = 0; d < 256; d += 4) {
        float hv0 = hrow[(d + 0) * SEQ];
        float hv1 = hrow[(d + 1) * SEQ];
        float hv2 = hrow[(d + 2) * SEQ];
        float hv3 = hrow[(d + 3) * SEQ];
        #pragma unroll
        for (int k = 0; k < 8; ++k) {
            float4 wv = *(const float4*)(in_w + (e0 + k) * 256 + d);
            acc[k] = fmaf(wv.x, hv0, fmaf(wv.y, hv1, fmaf(wv.z, hv2, fmaf(wv.w, hv3, acc[k]))));
        }
    }
    #pragma unroll
    for (int k = 0; k < 8; ++k)
        xz[(b * 1024 + e0 + k) * SEQ + l] = acc[k];
}

// ---------------- K2: causal dwconv(K=4) + silu, permuted x staged via swizzled LDS ----------------
__global__ __launch_bounds__(256) void k_conv(const float* __restrict__ xz,
                                              const float* __restrict__ conv_w,
                                              const float* __restrict__ conv_b,
                                              float* __restrict__ u){
    __shared__ float xs[2112];                         // swizzle: addr = j + (j>>5)
    int row = blockIdx.x;                              // ib*512 + d, ib = i*2+b
    int d = row & 511; int ib = row >> 9; int b = ib & 1; int i = ib >> 1;
    const int shtab[3] = {11, 6, 4};
    int sh = shtab[i >> 1];
    int mul = SEQ >> sh;                               // 1, 32, 128
    int inv = 11 - sh;                                 // log2(mul)
    int flip = i & 1;
    float w0 = conv_w[(i * 512 + d) * 4 + 0];
    float w1 = conv_w[(i * 512 + d) * 4 + 1];
    float w2 = conv_w[(i * 512 + d) * 4 + 2];
    float w3 = conv_w[(i * 512 + d) * 4 + 3];
    float cb = conv_b[i * 512 + d];
    const float* xrow = xz + (b * 1024 + d) * SEQ;
    float* urow = u + row * SEQ;
    #pragma unroll
    for (int k = 0; k < 8; ++k) {
        int l = (int)threadIdx.x + k * 256;
        float v = xrow[l];
        int jj = ((l & (mul - 1)) << sh) | (l >> inv); // inverse interleave
        if (flip) jj = 2047 - jj;
        xs[jj + (jj >> 5)] = v;
    }
    __syncthreads();
    #pragma unroll
    for (int k = 0; k < 8; ++k) {
        int j = (int)threadIdx.x + k * 256;
        float acc = cb;
        #pragma unroll
        for (int m = 0; m < 4; ++m) {
            int idx = j - 3 + m;
            float xv = 0.f;
            if (idx >= 0) xv = xs[idx + (idx >> 5)];
            float wm = (m == 0) ? w0 : (m == 1) ? w1 : (m == 2) ? w2 : w3;
            acc = fmaf(wm, xv, acc);
        }
        urow[j] = silu_f(acc);
    }
}

// ---------------- K3a: transpose xproj_w -> xwT[i][dd][r], i = 0..5 (all 6 branches!) ----------------
__global__ __launch_bounds__(256) void k_xwT(const float* __restrict__ xw,
                                             float* __restrict__ xwT){
    int t = blockIdx.x * 256 + threadIdx.x;            // 6*512*48 = 147456
    int r = t % 48; int dd = (t / 48) % 512; int i = t / (48 * 512);
    xwT[t] = xw[(i * 48 + r) * 512 + dd];
}

// ---------------- K3: xproj partial GEMM. block=(dq,jt,ib): 48 accs/thread, u read once ----------------
__global__ __launch_bounds__(256) void k_xproj2(const float* __restrict__ u,
                                                const float* __restrict__ xwT,
                                                float* __restrict__ xpart){
    int bid = blockIdx.x;                              // dq*96 + jt*12 + ib ; 384 blocks
    int ib = bid % 12; int jt = (bid / 12) % 8; int dq = bid / 96;
    int j = jt * 256 + (int)threadIdx.x;
    int i = ib >> 1;
    const float* ub = u + ((size_t)ib * 512 + dq * 128) * SEQ + j;
    const float* wb = xwT + ((size_t)i * 512 + dq * 128) * 48;
    float acc[48];
    #pragma unroll
    for (int r = 0; r < 48; ++r) acc[r] = 0.f;
    for (int dd = 0; dd < 128; ++dd) {
        float uv = ub[dd * SEQ];
        const float* w = wb + dd * 48;                 // block-uniform -> s_loads
        #pragma unroll
        for (int r = 0; r < 48; ++r)
            acc[r] = fmaf(w[r], uv, acc[r]);
    }
    float* op = xpart + ((size_t)(dq * 12 + ib) * 48) * SEQ + j;
    #pragma unroll
    for (int r = 0; r < 48; ++r) op[r * SEQ] = acc[r];
}

// ---------------- K3c: reduce partials -> xdbl ----------------
__global__ __launch_bounds__(256) void k_xred(const float* __restrict__ xpart,
                                              float* __restrict__ xdbl){
    int t = blockIdx.x * 256 + threadIdx.x;            // 12*48*2048 = 1179648
    const int STR = 12 * 48 * SEQ;
    xdbl[t] = (xpart[t] + xpart[t + STR]) + (xpart[t + 2 * STR] + xpart[t + 3 * STR]);
}

// ---------------- K3b: transpose B/C rows to btct[ib][j][32] (B: q=0..15, C: q=16..31) ----------------
__global__ __launch_bounds__(256) void k_btct(const float* __restrict__ xdbl,
                                              float* __restrict__ btct){
    int t = blockIdx.x * 256 + threadIdx.x;            // 12*32*2048 = 786432
    int j = t & 2047; int q = (t >> 11) & 31; int ib = t >> 16;
    btct[((ib * 2048 + j) << 5) + q] = xdbl[(ib * 48 + 16 + q) * 2048 + j];
}

// ---------------- K4: delta[ib][d][j] = softplus(dtlow . dt_w[d] + dt_b[d]) ----------------
__global__ __launch_bounds__(256) void k_delta(const float* __restrict__ xdbl,
                                               const float* __restrict__ dt_w,
                                               const float* __restrict__ dt_b,
                                               float* __restrict__ delta){
    int t = blockIdx.x * 256 + threadIdx.x;            // (ib*128 + d4)*2048 + j
    int j = t & 2047;
    int d4 = (t >> 11) & 127;
    int ib = t >> 18; int i = ib >> 1;
    const float* dl = xdbl + ib * 48 * SEQ + j;        // dtlow rows r=0..15
    const float* w = dt_w + (i * 512 + d4 * 4) * 16;
    float a0 = 0, a1 = 0, a2 = 0, a3 = 0;
    #pragma unroll
    for (int r = 0; r < 16; ++r) {
        float v = dl[r * SEQ];
        a0 = fmaf(w[r],      v, a0);
        a1 = fmaf(w[16 + r], v, a1);
        a2 = fmaf(w[32 + r], v, a2);
        a3 = fmaf(w[48 + r], v, a3);
    }
    float accs[4] = {a0, a1, a2, a3};
    #pragma unroll
    for (int k = 0; k < 4; ++k) {
        float x = accs[k] + dt_b[i * 512 + d4 * 4 + k];
        float sp = fmaxf(x, 0.f) + __logf(1.f + __expf(-fabsf(x)));
        delta[(ib * 512 + d4 * 4 + k) * SEQ + j] = sp;
    }
}

// ---------------- K5: chunked SSM scan, swizzled LDS (conflict-free) ----------------
// LDS element addr = j + 4*(j>>7): per-chunk base lands on bank 4*cc -> the 4 cc-groups
// of a wave read 4 distinct banks (16-lane broadcast within a group is free).
__global__ __launch_bounds__(256) void k_scan(float* __restrict__ u,
                                              const float* __restrict__ delta,
                                              const float* __restrict__ btct,
                                              const float* __restrict__ A_log,
                                              const float* __restrict__ D_skip){
    __shared__ float sdelta[2112];                     // 2048 + 16*4 pad
    __shared__ float su[2112];
    __shared__ float sh[256];                          // h_end[cc][n]
    __shared__ float sh0[256];                         // h0[cc][n]
    __shared__ float sS[16];                           // sum(delta) per chunk
    int w = blockIdx.x;                                // ib*512 + d
    int tid = threadIdx.x;
    int cc = tid >> 4;                                 // chunk 0..15
    int n  = tid & 15;                                 // state 0..15
    int d = w & 511; int ib = w >> 9; int i = ib >> 1;
    float A = -__expf(A_log[(i * 512 + d) * 16 + n]);
    float Dd = D_skip[i * 512 + d];

    const float4* dg4 = (const float4*)(delta + (size_t)w * SEQ);
    float4* ug4 = (float4*)(u + (size_t)w * SEQ);
    float4* sd4 = (float4*)sdelta;
    float4* su4 = (float4*)su;
    {
        int t2 = tid + 256;
        sd4[tid + (tid >> 5)] = dg4[tid];
        sd4[t2 + (t2 >> 5)]   = dg4[t2];
        su4[tid + (tid >> 5)] = ug4[tid];
        su4[t2 + (t2 >> 5)]   = ug4[t2];
    }
    __syncthreads();

    const float* sd = sdelta + cc * 132;               // swizzled chunk base
    float* suc = su + cc * 132;
    const float* bp = btct + ((size_t)(ib * 2048 + cc * 128) << 5) + n;  // [j][32]

    // Phase 1: local scan, h0 = 0
    float h = 0.f, S = 0.f;
    #pragma unroll 4
    for (int t = 0; t < 128; ++t) {
        float dlt = sd[t];
        float uu  = suc[t];
        float b   = bp[t * 32];
        float e = __expf(dlt * A);
        h = fmaf(e, h, dlt * uu * b);
        S += dlt;
    }
    sh[cc * 16 + n] = h;
    if (n == 0) sS[cc] = S;
    __syncthreads();

    // Phase 2: serial cross-chunk combine (threads 0..15, one per state)
    if (tid < 16) {
        float h0 = 0.f;
        #pragma unroll
        for (int c = 0; c < 16; ++c) {
            sh0[c * 16 + tid] = h0;
            h0 = fmaf(__expf(A * sS[c]), h0, sh[c * 16 + tid]);
        }
    }
    __syncthreads();

    // Phase 3: rescan with true h0; y = red16(h*C); overwrite su with y
    h = sh0[cc * 16 + n];
    #pragma unroll 4
    for (int t = 0; t < 128; ++t) {
        float dlt = sd[t];
        float uu  = suc[t];
        float b   = bp[t * 32];
        float cv  = bp[t * 32 + 16];
        float e = __expf(dlt * A);
        h = fmaf(e, h, dlt * uu * b);
        float y = red16(h * cv);
        if (n == 0) suc[t] = fmaf(uu, Dd, y);
    }
    __syncthreads();

    {
        int t2 = tid + 256;
        ug4[tid] = su4[tid + (tid >> 5)];
        ug4[t2]  = su4[t2 + (t2 >> 5)];
    }
}

// ---------------- K6: un-permute, sum branches, silu(z) fused; LDS-staged permuted rows ----------------
__global__ __launch_bounds__(256) void k_gather(const float* __restrict__ y,
                                                const float* __restrict__ xz,
                                                float* __restrict__ total){
    __shared__ float s2[2112], s3[2112], s4[2112], s5[2112];
    int bid = blockIdx.x;                              // b*512 + d ; 1024 blocks
    int d = bid & 511; int b = bid >> 9;
    long base = (long)(b * 512 + d) * SEQ;
    const float* y0 = y + (0 * 1024) * SEQ + base;
    const float* y1 = y + (1 * 1024) * SEQ + base;
    const float* y2r = y + (2 * 1024) * SEQ + base;
    const float* y3r = y + (3 * 1024) * SEQ + base;
    const float* y4r = y + (4 * 1024) * SEQ + base;
    const float* y5r = y + (5 * 1024) * SEQ + base;
    #pragma unroll
    for (int k = 0; k < 8; ++k) {
        int j = (int)threadIdx.x + k * 256;
        int a = j + (j >> 5);
        s2[a] = y2r[j];
        s3[a] = y3r[j];
        s4[a] = y4r[j];
        s5[a] = y5r[j];
    }
    __syncthreads();
    const float* zrow = xz + (b * 1024 + 512 + d) * SEQ;
    float* trow = total + (b * 512 + d) * SEQ;
    #pragma unroll
    for (int k = 0; k < 8; ++k) {
        int l = (int)threadIdx.x + k * 256;
        int j2 = ((l & 31) << 6) | (l >> 5);           // interleave ns=64 read index
        int j4 = ((l & 127) << 4) | (l >> 7);          // interleave ns=16 read index
        int a2 = j2 + (j2 >> 5);
        int a4 = j4 + (j4 >> 5);
        float s_fwd = y0[l] + y1[2047 - l] + s2[a2] + s4[a4];
        float s_bwd = s3[a2] + s5[a4];
        float zl = silu_f(zrow[l]);
        float zr = silu_f(zrow[2047 - l]);
        trow[l] = fmaf(s_fwd, zl, s_bwd * zr);
    }
}

// ---------------- K7: out[b][l][o] = sum_d total[b][d][l] * out_w[o][d] ----------------
__global__ __launch_bounds__(256) void k_outgemm(const float* __restrict__ total,
                                                 const float* __restrict__ out_w,
                                                 float* __restrict__ out){
    int lane = threadIdx.x & 63;
    int ow = threadIdx.x >> 6;                         // 0..3
    int bid = blockIdx.x;                              // 2*8*32
    int lblk = bid & 31; int oblk = (bid >> 5) & 7; int b = bid >> 8;
    int l = lblk * 64 + lane;
    int o0 = oblk * 32 + ow * 8;
    const float* trow = total + b * 512 * SEQ + l;
    float acc[8] = {0,0,0,0,0,0,0,0};
    for (int d = 0; d < 512; d += 4) {
        float t0 = trow[(d + 0) * SEQ];
        float t1 = trow[(d + 1) * SEQ];
        float t2 = trow[(d + 2) * SEQ];
        float t3 = trow[(d + 3) * SEQ];
        #pragma unroll
        for (int k = 0; k < 8; ++k) {
            float4 wv = *(const float4*)(out_w + (o0 + k) * 512 + d);
            acc[k] = fmaf(wv.x, t0, fmaf(wv.y, t1, fmaf(wv.z, t2, fmaf(wv.w, t3, acc[k]))));
        }
    }
    float* orow = out + ((long)(b * 2048 + l)) * 256 + o0;
    #pragma unroll
    for (int k = 0; k < 8; ++k) orow[k] = acc[k];
}

extern "C" void kernel_launch(void* const* d_in, const int* in_sizes, int n_in,
                              void* d_out, int out_size, void* d_ws, size_t ws_size,
                              hipStream_t stream) {
    const float* hid    = (const float*)d_in[0];
    const float* in_w   = (const float*)d_in[1];
    const float* out_w  = (const float*)d_in[2];
    const float* conv_w = (const float*)d_in[3];
    const float* conv_b = (const float*)d_in[4];
    const float* xw     = (const float*)d_in[5];
    const float* dt_w   = (const float*)d_in[6];
    const float* dt_b   = (const float*)d_in[7];
    const float* A_log  = (const float*)d_in[8];
    const float* D_skip = (const float*)d_in[9];
    float* out = (float*)d_out;

    // ws layout (floats)
    const size_t off_xz    = 0;                        // 2*1024*2048  = 4,194,304
    const size_t off_u     = 4194304;                  // 12*512*2048  = 12,582,912
    const size_t off_xdbl  = 16777216;                 // 12*48*2048   = 1,179,648
    const size_t off_delta = 17956864;                 // 12,582,912
    const size_t off_total = 30539776;                 // 2*512*2048   = 2,097,152
    const size_t need = (size_t)32636928 * 4;
    if (ws_size < need) return;

    float* xz    = (float*)d_ws + off_xz;
    float* u     = (float*)d_ws + off_u;
    float* xdbl  = (float*)d_ws + off_xdbl;
    float* delta = (float*)d_ws + off_delta;
    float* total = (float*)d_ws + off_total;
    // region time-sharing:
    //   total region: hidT (until k_ingemm) -> btct@+0 (786432) + xwT@+786432 (147456) -> total
    //   delta region: xpart (k_xproj2..k_xred, 4.7M floats) -> delta (k_delta on)
    float* hidT  = total;
    float* btct  = total;
    float* xwT   = total + 786432;
    float* xpart = delta;

    k_transpose<<<256,  256, 0, stream>>>(hid, hidT);
    k_ingemm  <<<2048, 256, 0, stream>>>(hidT, in_w, xz);
    k_xwT     <<<576,  256, 0, stream>>>(xw, xwT);     // 6*512*48 = 147456 elems
    k_conv    <<<6144, 256, 0, stream>>>(xz, conv_w, conv_b, u);
    k_xproj2  <<<384,  256, 0, stream>>>(u, xwT, xpart);
    k_xred    <<<4608, 256, 0, stream>>>(xpart, xdbl);
    k_btct    <<<3072, 256, 0, stream>>>(xdbl, btct);
    k_delta   <<<12288,256, 0, stream>>>(xdbl, dt_w, dt_b, delta);
    k_scan    <<<6144, 256, 0, stream>>>(u, delta, btct, A_log, D_skip);
    k_gather  <<<1024, 256, 0, stream>>>(u, xz, total);
    k_outgemm <<<512,  256, 0, stream>>>(total, out_w, out);
}